// Round 7
// baseline (659.389 us; speedup 1.0000x reference)
//
#include <hip/hip_runtime.h>
#include <hip/hip_bf16.h>
#include <math.h>

#define N_NODES 50000
#define N_EDGES 800000
#define SCAN_B 196            // 196 blocks x 256 = 50176 >= N_NODES

typedef __hip_bfloat16 bf16;
typedef __attribute__((ext_vector_type(8))) short frag_ab;   // 8 bf16
typedef __attribute__((ext_vector_type(4))) float frag_cd;   // 4 f32

__device__ __forceinline__ float b2f(bf16 v){ return __bfloat162float(v); }
__device__ __forceinline__ bf16 f2b(float v){ return __float2bfloat16(v); }
// 1-op-per-element bf16x2 decode: lo = u<<16, hi = u & 0xFFFF0000
__device__ __forceinline__ void ld4dec(uint2 u, float f[4]){
    f[0] = __uint_as_float(u.x << 16);
    f[1] = __uint_as_float(u.x & 0xFFFF0000u);
    f[2] = __uint_as_float(u.y << 16);
    f[3] = __uint_as_float(u.y & 0xFFFF0000u);
}
__device__ __forceinline__ void ld4bf(const bf16* p, float f[4]){
    ld4dec(*(const uint2*)p, f);
}
__device__ __forceinline__ float ldrt(const void* p, size_t i, bool f32){
    return f32 ? ((const float*)p)[i] : b2f(((const bf16*)p)[i]);
}

// flags[0] = edge_index is int64; flags[1] = float tensors are float32
__global__ __launch_bounds__(256) void detect_kernel(
    const int* __restrict__ ei, const unsigned int* __restrict__ xw,
    int* __restrict__ flags){
    __shared__ int s64, sf32;
    const int t = threadIdx.x;
    if (t == 0){ s64 = 1; sf32 = 0; }
    __syncthreads();
    if (ei[2*t + 1] != 0) s64 = 0;                 // benign race: all write 0
    if (t < 64){
        unsigned int w = xw[t];
        float lo = __uint_as_float((w & 0xFFFFu) << 16);
        if (!(fabsf(lo) <= 64.f)) sf32 = 1;        // benign race
    }
    __syncthreads();
    if (t == 0){ flags[0] = s64; flags[1] = sf32; }
}

// ---- convert x -> bf16 xb [N,128] ------------------------------------------
__global__ __launch_bounds__(256) void conv_x(const void* __restrict__ xin,
                                              bf16* __restrict__ xb,
                                              const int* __restrict__ flags){
    const size_t i = ((size_t)blockIdx.x*256 + threadIdx.x) * 8;
    if (i >= (size_t)N_NODES*128) return;
    if (flags[1]){
        const float* xf = (const float*)xin;
        #pragma unroll
        for (int j = 0; j < 8; ++j) xb[i+j] = f2b(xf[i+j]);
    } else {
        *(uint4*)(xb + i) = *(const uint4*)((const bf16*)xin + i);
    }
}

// ---- convert 6 small vectors (256 each) -> f32 -----------------------------
__global__ void conv_vec6(const void* p0, const void* p1, const void* p2,
                          const void* p3, const void* p4, const void* p5,
                          float* __restrict__ outv, const int* __restrict__ flags){
    const int t = threadIdx.x;
    const bool f32 = flags[1] != 0;
    outv[0*256+t] = ldrt(p0, t, f32);
    outv[1*256+t] = ldrt(p1, t, f32);
    outv[2*256+t] = ldrt(p2, t, f32);
    outv[3*256+t] = ldrt(p3, t, f32);
    outv[4*256+t] = ldrt(p4, t, f32);
    outv[5*256+t] = ldrt(p5, t, f32);
}

// ---- CSR build: histogram -> 3-phase parallel scan -> scatter --------------
__global__ __launch_bounds__(256) void hist_kernel(const int* __restrict__ ei,
                                                   int* __restrict__ counts,
                                                   const int* __restrict__ flags){
    const int e = blockIdx.x*256 + threadIdx.x;
    if (e >= N_EDGES) return;
    const bool i64 = flags[0] != 0;
    const int src = i64 ? ei[2*e]             : ei[e];
    const int dst = i64 ? ei[2*(N_EDGES + e)] : ei[N_EDGES + e];
    if ((unsigned)src >= N_NODES || (unsigned)dst >= N_NODES) return;
    atomicAdd(&counts[dst], 1);
}

__global__ __launch_bounds__(256) void scan_phase1(const int* __restrict__ counts,
                                                   int* __restrict__ bsum){
    __shared__ int ws[4];
    const int idx = blockIdx.x*256 + threadIdx.x;
    int v = (idx < N_NODES) ? counts[idx] : 0;
    const int lane = threadIdx.x & 63, wid = threadIdx.x >> 6;
    #pragma unroll
    for (int off = 1; off < 64; off <<= 1) v += __shfl_xor(v, off, 64);
    if (lane == 0) ws[wid] = v;
    __syncthreads();
    if (threadIdx.x == 0) bsum[blockIdx.x] = ws[0]+ws[1]+ws[2]+ws[3];
}

__global__ __launch_bounds__(256) void scan_phase2(const int* __restrict__ bsum,
                                                   int* __restrict__ bbase){
    __shared__ int ws[4];
    const int t = threadIdx.x;
    const int lane = t & 63, wid = t >> 6;
    int v = (t < SCAN_B) ? bsum[t] : 0;
    int incl = v;
    #pragma unroll
    for (int off = 1; off < 64; off <<= 1){
        const int u = __shfl_up(incl, off, 64);
        if (lane >= off) incl += u;
    }
    if (lane == 63) ws[wid] = incl;
    __syncthreads();
    int wb = 0;
    for (int j = 0; j < wid; ++j) wb += ws[j];
    if (t < SCAN_B) bbase[t] = wb + incl - v;   // exclusive
}

__global__ __launch_bounds__(256) void scan_phase3(const int* __restrict__ counts,
                                                   const int* __restrict__ bbase,
                                                   int* __restrict__ offsets,
                                                   int* __restrict__ cursor){
    __shared__ int ws[4];
    const int idx = blockIdx.x*256 + threadIdx.x;
    const int lane = threadIdx.x & 63, wid = threadIdx.x >> 6;
    const int v = (idx < N_NODES) ? counts[idx] : 0;
    int incl = v;
    #pragma unroll
    for (int off = 1; off < 64; off <<= 1){
        const int u = __shfl_up(incl, off, 64);
        if (lane >= off) incl += u;
    }
    if (lane == 63) ws[wid] = incl;
    __syncthreads();
    int wb = bbase[blockIdx.x];
    for (int j = 0; j < wid; ++j) wb += ws[j];
    const int excl = wb + incl - v;
    if (idx < N_NODES){
        offsets[idx] = excl; cursor[idx] = excl;
        if (idx == N_NODES-1) offsets[N_NODES] = excl + v;
    }
}

// edges[pos] = (src*1536 byte offset into P, eav bits)
__global__ __launch_bounds__(256) void scatter_kernel(
    const int* __restrict__ ei, const void* __restrict__ ea,
    int* __restrict__ cursor, int2* __restrict__ edges,
    const int* __restrict__ flags){
    const int e = blockIdx.x*256 + threadIdx.x;
    if (e >= N_EDGES) return;
    const bool i64 = flags[0] != 0, f32 = flags[1] != 0;
    const int src = i64 ? ei[2*e]             : ei[e];
    const int dst = i64 ? ei[2*(N_EDGES + e)] : ei[N_EDGES + e];
    if ((unsigned)src >= N_NODES || (unsigned)dst >= N_NODES) return;
    const float eav = f32 ? ((const float*)ea)[e] : b2f(((const bf16*)ea)[e]);
    const int pos = atomicAdd(&cursor[dst], 1);
    edges[pos] = make_int2(src * 1536, __float_as_int(eav));
}

// ---- transpose 4 weight mats [K,256] -> Wt[1024][K] bf16, biases -> f32 ----
template<int K>
__global__ __launch_bounds__(256) void trans_w(
    const void* w0, const void* w1, const void* w2, const void* w3,
    const void* b0, const void* b1, const void* b2, const void* b3,
    bf16* __restrict__ Wt, float* __restrict__ biasf,
    const int* __restrict__ flags)
{
    const bool f32 = flags[1] != 0;
    const int mi = blockIdx.y;
    const void* W = mi==0?w0 : mi==1?w1 : mi==2?w2 : w3;
    const void* B = mi==0?b0 : mi==1?b1 : mi==2?b2 : b3;
    const int t = threadIdx.x;
    if (blockIdx.x == 0) biasf[mi*256 + t] = ldrt(B, t, f32);
    if (t >= K) return;
    const int c0 = blockIdx.x * 16;
    for (int c = c0; c < c0 + 16; ++c)
        Wt[(size_t)(mi*256 + c)*K + t] = f2b(ldrt(W, (size_t)t*256 + c, f32));
}

// ---- MFMA GEMM: P[:, 0:768] = X@W(qkv)+b (stride 768), cols 768.. -> skipb --
#define AST 40
template<int K>
__global__ __launch_bounds__(256) void gemm_qkvs(
    const bf16* __restrict__ X, const bf16* __restrict__ Wt,
    const float* __restrict__ bias,
    bf16* __restrict__ P, bf16* __restrict__ skipb)
{
    __shared__ short As[64*AST];
    __shared__ short Bs[64*AST];
    const int t = threadIdx.x;
    const int wid = t >> 6, lane = t & 63;
    const int quad = lane >> 4, l16 = lane & 15;
    const int m0 = blockIdx.x * 64;
    const int n0 = blockIdx.y * 64;
    const int srow = t >> 2;
    const int scg  = (t & 3) * 8;
    const int arow = m0 + srow;

    frag_cd acc[4] = {};
    for (int k0 = 0; k0 < K; k0 += 32){
        uint4 av = {0,0,0,0};
        if (arow < N_NODES)
            av = *(const uint4*)(X + (size_t)arow*K + k0 + scg);
        *(uint4*)(&As[srow*AST + scg]) = av;
        uint4 bv = *(const uint4*)(Wt + (size_t)(n0 + srow)*K + k0 + scg);
        *(uint4*)(&Bs[srow*AST + scg]) = bv;
        __syncthreads();
        frag_ab af = *(const frag_ab*)(&As[(wid*16 + l16)*AST + quad*8]);
        #pragma unroll
        for (int nt = 0; nt < 4; ++nt){
            frag_ab bfr = *(const frag_ab*)(&Bs[(nt*16 + l16)*AST + quad*8]);
            acc[nt] = __builtin_amdgcn_mfma_f32_16x16x32_bf16(af, bfr, acc[nt], 0, 0, 0);
        }
        __syncthreads();
    }
    #pragma unroll
    for (int nt = 0; nt < 4; ++nt){
        const int gc = n0 + nt*16 + l16;
        const float bsum = bias[gc];
        #pragma unroll
        for (int r = 0; r < 4; ++r){
            const int node = m0 + wid*16 + quad*4 + r;
            if (node < N_NODES){
                const float y = acc[nt][r] + bsum;
                if (gc < 768) P[(size_t)node*768 + gc] = f2b(y);
                else          skipb[(size_t)node*256 + (gc - 768)] = f2b(y);
            }
        }
    }
}

// ---- fused per-node attention + softmax + skip + LN (+ReLU) ----------------
// One wave per dst node; lane owns channels c = lane*4..+3.
// Algebra: q.(k+eav*ew) = q.k + eav*(q.ew);  sum a*(v+eav*ew) = sum a*v + ew*sum(a*eav)
template<int HEADS, bool RELU, bool OUTDYN>
__global__ __launch_bounds__(256) void node_attn(
    const bf16* __restrict__ P,          // [N,768] q|k|v
    const int2* __restrict__ edges,      // dst-sorted (src*1536, eav)
    const int* __restrict__ offsets,     // [N+1]
    const bf16* __restrict__ skip,       // [N,256]
    const float* __restrict__ ewf,
    const float* __restrict__ gf, const float* __restrict__ bf_,
    void* __restrict__ out, const int* __restrict__ flags)
{
    const int node = blockIdx.x*4 + (threadIdx.x >> 6);
    if (node >= N_NODES) return;
    const int lane = threadIdx.x & 63;
    const int c0 = lane * 4;
    const float scale = (HEADS == 4) ? 0.125f : 0.0625f;
    const int RED = (HEADS == 4) ? 16 : 64;

    float q4[4], ew4[4];
    ld4bf(P + (size_t)node*768 + c0, q4);
    ew4[0] = ewf[c0]; ew4[1] = ewf[c0+1]; ew4[2] = ewf[c0+2]; ew4[3] = ewf[c0+3];

    // per-head (q . ew) * scale, broadcast within head group
    float qe = q4[0]*ew4[0] + q4[1]*ew4[1] + q4[2]*ew4[2] + q4[3]*ew4[3];
    #pragma unroll
    for (int off = 1; off < 64; off <<= 1)
        if (off < RED) qe += __shfl_xor(qe, off, 64);
    const float qewS = qe * scale;

    const int beg = offsets[node], end = offsets[node+1];
    float s = 0.f, seav = 0.f;
    float macc[4] = {0.f, 0.f, 0.f, 0.f};

    const char* base = (const char*)P + 512 + 2*c0;   // + src*1536 -> k chans c0..
    if (beg < end){
        int2 rec = edges[beg];
        uint2 ku = *(const uint2*)(base + (size_t)(unsigned)rec.x);
        uint2 vu = *(const uint2*)(base + (size_t)(unsigned)rec.x + 512);
        for (int e = beg; e < end; ++e){
            // software pipeline: issue next gather before current compute
            const int2 nrec = (e + 1 < end) ? edges[e+1] : rec;
            const uint2 ku2 = *(const uint2*)(base + (size_t)(unsigned)nrec.x);
            const uint2 vu2 = *(const uint2*)(base + (size_t)(unsigned)nrec.x + 512);
            const float eav = __int_as_float(rec.y);
            float kf[4];
            ld4dec(ku, kf);
            float p = q4[0]*kf[0] + q4[1]*kf[1] + q4[2]*kf[2] + q4[3]*kf[3];
            #pragma unroll
            for (int off = 1; off < 64; off <<= 1)
                if (off < RED) p += __shfl_xor(p, off, 64);
            const float a = expf(fminf(fmaf(p, scale, eav*qewS), 80.f));
            s += a;
            seav = fmaf(a, eav, seav);
            float vf[4];
            ld4dec(vu, vf);
            macc[0] = fmaf(a, vf[0], macc[0]);
            macc[1] = fmaf(a, vf[1], macc[1]);
            macc[2] = fmaf(a, vf[2], macc[2]);
            macc[3] = fmaf(a, vf[3], macc[3]);
            rec = nrec; ku = ku2; vu = vu2;
        }
    }

    const float rdenom = 1.f / (s + 1e-16f);
    float sk[4];
    ld4bf(skip + (size_t)node*256 + c0, sk);
    float val[4];
    #pragma unroll
    for (int j = 0; j < 4; ++j)
        val[j] = fmaf(ew4[j], seav, macc[j]) * rdenom + sk[j];

    float sum = val[0]+val[1]+val[2]+val[3];
    #pragma unroll
    for (int off = 1; off < 64; off <<= 1) sum += __shfl_xor(sum, off, 64);
    const float mu = sum * (1.f/256.f);
    float vs = 0.f;
    #pragma unroll
    for (int j = 0; j < 4; ++j){ const float d = val[j]-mu; vs += d*d; }
    #pragma unroll
    for (int off = 1; off < 64; off <<= 1) vs += __shfl_xor(vs, off, 64);
    const float rstd = rsqrtf(vs * (1.f/256.f) + 1e-5f);

    float y[4];
    #pragma unroll
    for (int j = 0; j < 4; ++j){
        y[j] = (val[j]-mu) * rstd * gf[c0+j] + bf_[c0+j];
        if (RELU) y[j] = fmaxf(y[j], 0.f);
    }
    const bool of32 = OUTDYN && (flags[1] != 0);
    if (of32){
        float4 o = {y[0], y[1], y[2], y[3]};
        *(float4*)((float*)out + (size_t)node*256 + c0) = o;
    } else {
        uint2 o;
        o.x = ((unsigned)__bfloat16_as_ushort(f2b(y[0]))) |
              (((unsigned)__bfloat16_as_ushort(f2b(y[1]))) << 16);
        o.y = ((unsigned)__bfloat16_as_ushort(f2b(y[2]))) |
              (((unsigned)__bfloat16_as_ushort(f2b(y[3]))) << 16);
        *(uint2*)((bf16*)out + (size_t)node*256 + c0) = o;
    }
}

extern "C" void kernel_launch(void* const* d_in, const int* in_sizes, int n_in,
                              void* d_out, int out_size, void* d_ws, size_t ws_size,
                              hipStream_t stream) {
    const int* ei = (const int*)d_in[1];

    // ---- workspace layout (bytes), peak ~110 MB ----
    char* w = (char*)d_ws;
    bf16*  P       = (bf16*) (w + 0);            // [N,768] (76.8MB)
    bf16*  xb      = (bf16*) (w + 76800000);     // [N,128] (dead after GEMM0)
    bf16*  skipL1  = (bf16*) (w + 76800000);     // [N,256] (born at GEMM1)
    bf16*  Wt      = (bf16*) (w + 102400000);    // 1024*256*2 = 524288
    float* biasf   = (float*)(w + 102924288);    // 4KB
    int*   counts  = (int*)  (w + 102928384);    // 200KB
    int*   offsets = (int*)  (w + 103128384);    // 200KB+4
    int*   cursor  = (int*)  (w + 103328388);    // 200KB
    int2*  edges   = (int2*) (w + 103528392);    // 6.4MB
    float* vecs    = (float*)(w + 109928400);    // 6x256 f32
    int*   flags   = (int*)  (w + 109934544);
    int*   bsum    = (int*)  (w + 109934608);    // SCAN_B ints
    int*   bbase   = (int*)  (w + 109935392);    // SCAN_B ints
    float* ewf0 = vecs + 0,   *ewf1 = vecs + 256;
    float* gf0  = vecs + 512, *bf0  = vecs + 768;
    float* gf1  = vecs + 1024,*bf1  = vecs + 1280;
    bf16*  skipL0 = (bf16*)d_out;   // d_out as scratch: skip -> h in-place
    bf16*  hbuf   = (bf16*)d_out;

    const int EB = (N_EDGES + 255) / 256;
    const int NB = (N_NODES + 3) / 4;

    detect_kernel<<<1, 256, 0, stream>>>(ei, (const unsigned int*)d_in[0], flags);
    hipMemsetAsync(counts, 0, (size_t)N_NODES*4, stream);
    conv_x<<<3125, 256, 0, stream>>>(d_in[0], xb, flags);
    conv_vec6<<<1, 256, 0, stream>>>(d_in[9], d_in[20], d_in[12], d_in[13],
                                     d_in[23], d_in[24], vecs, flags);
    // CSR build (once, shared by both layers)
    hist_kernel<<<EB, 256, 0, stream>>>(ei, counts, flags);
    scan_phase1<<<SCAN_B, 256, 0, stream>>>(counts, bsum);
    scan_phase2<<<1, 256, 0, stream>>>(bsum, bbase);
    scan_phase3<<<SCAN_B, 256, 0, stream>>>(counts, bbase, offsets, cursor);
    scatter_kernel<<<EB, 256, 0, stream>>>(ei, d_in[2], cursor, edges, flags);

    // ---------------- layer 0 ----------------
    trans_w<128><<<dim3(16,4), 256, 0, stream>>>(
        d_in[3], d_in[5], d_in[7], d_in[10],
        d_in[4], d_in[6], d_in[8], d_in[11],
        Wt, biasf, flags);
    gemm_qkvs<128><<<dim3(782,16), 256, 0, stream>>>(xb, Wt, biasf, P, skipL0);
    node_attn<4, true, false><<<NB, 256, 0, stream>>>(
        P, edges, offsets, skipL0, ewf0, gf0, bf0, hbuf, flags);

    // ---------------- layer 1 ----------------
    trans_w<256><<<dim3(16,4), 256, 0, stream>>>(
        d_in[14], d_in[16], d_in[18], d_in[21],
        d_in[15], d_in[17], d_in[19], d_in[22],
        Wt, biasf, flags);
    gemm_qkvs<256><<<dim3(782,16), 256, 0, stream>>>(hbuf, Wt, biasf, P, skipL1);
    node_attn<1, false, true><<<NB, 256, 0, stream>>>(
        P, edges, offsets, skipL1, ewf1, gf1, bf1, d_out, flags);
}

// Round 8
// 627.225 us; speedup vs baseline: 1.0513x; 1.0513x over previous
//
#include <hip/hip_runtime.h>
#include <hip/hip_bf16.h>
#include <math.h>

#define N_NODES 50000
#define N_EDGES 800000
#define SCAN_B 196            // 196 blocks x 256 = 50176 >= N_NODES

typedef __hip_bfloat16 bf16;
typedef __attribute__((ext_vector_type(8))) short frag_ab;   // 8 bf16
typedef __attribute__((ext_vector_type(4))) float frag_cd;   // 4 f32

__device__ __forceinline__ float b2f(bf16 v){ return __bfloat162float(v); }
__device__ __forceinline__ bf16 f2b(float v){ return __float2bfloat16(v); }
// 1-op-per-element bf16x2 decode: lo = u<<16, hi = u & 0xFFFF0000
__device__ __forceinline__ void ld4dec(uint2 u, float f[4]){
    f[0] = __uint_as_float(u.x << 16);
    f[1] = __uint_as_float(u.x & 0xFFFF0000u);
    f[2] = __uint_as_float(u.y << 16);
    f[3] = __uint_as_float(u.y & 0xFFFF0000u);
}
__device__ __forceinline__ void ld4bf(const bf16* p, float f[4]){
    ld4dec(*(const uint2*)p, f);
}
__device__ __forceinline__ float ldrt(const void* p, size_t i, bool f32){
    return f32 ? ((const float*)p)[i] : b2f(((const bf16*)p)[i]);
}

// flags[0] = edge_index is int64; flags[1] = float tensors are float32
__global__ __launch_bounds__(256) void detect_kernel(
    const int* __restrict__ ei, const unsigned int* __restrict__ xw,
    int* __restrict__ flags){
    __shared__ int s64, sf32;
    const int t = threadIdx.x;
    if (t == 0){ s64 = 1; sf32 = 0; }
    __syncthreads();
    if (ei[2*t + 1] != 0) s64 = 0;                 // benign race: all write 0
    if (t < 64){
        unsigned int w = xw[t];
        float lo = __uint_as_float((w & 0xFFFFu) << 16);
        if (!(fabsf(lo) <= 64.f)) sf32 = 1;        // benign race
    }
    __syncthreads();
    if (t == 0){ flags[0] = s64; flags[1] = sf32; }
}

// ---- convert x -> bf16 xb [N,128] ------------------------------------------
__global__ __launch_bounds__(256) void conv_x(const void* __restrict__ xin,
                                              bf16* __restrict__ xb,
                                              const int* __restrict__ flags){
    const size_t i = ((size_t)blockIdx.x*256 + threadIdx.x) * 8;
    if (i >= (size_t)N_NODES*128) return;
    if (flags[1]){
        const float* xf = (const float*)xin;
        #pragma unroll
        for (int j = 0; j < 8; ++j) xb[i+j] = f2b(xf[i+j]);
    } else {
        *(uint4*)(xb + i) = *(const uint4*)((const bf16*)xin + i);
    }
}

// ---- convert 6 small vectors (256 each) -> f32 -----------------------------
__global__ void conv_vec6(const void* p0, const void* p1, const void* p2,
                          const void* p3, const void* p4, const void* p5,
                          float* __restrict__ outv, const int* __restrict__ flags){
    const int t = threadIdx.x;
    const bool f32 = flags[1] != 0;
    outv[0*256+t] = ldrt(p0, t, f32);
    outv[1*256+t] = ldrt(p1, t, f32);
    outv[2*256+t] = ldrt(p2, t, f32);
    outv[3*256+t] = ldrt(p3, t, f32);
    outv[4*256+t] = ldrt(p4, t, f32);
    outv[5*256+t] = ldrt(p5, t, f32);
}

// ---- CSR build: histogram -> 3-phase parallel scan -> scatter --------------
__global__ __launch_bounds__(256) void hist_kernel(const int* __restrict__ ei,
                                                   int* __restrict__ counts,
                                                   const int* __restrict__ flags){
    const int e = blockIdx.x*256 + threadIdx.x;
    if (e >= N_EDGES) return;
    const bool i64 = flags[0] != 0;
    const int dst = i64 ? ((const int2*)ei)[N_EDGES + e].x : ei[N_EDGES + e];
    if ((unsigned)dst >= N_NODES) return;
    atomicAdd(&counts[dst], 1);
}

__global__ __launch_bounds__(256) void scan_phase1(const int* __restrict__ counts,
                                                   int* __restrict__ bsum){
    __shared__ int ws[4];
    const int idx = blockIdx.x*256 + threadIdx.x;
    int v = (idx < N_NODES) ? counts[idx] : 0;
    const int lane = threadIdx.x & 63, wid = threadIdx.x >> 6;
    #pragma unroll
    for (int off = 1; off < 64; off <<= 1) v += __shfl_xor(v, off, 64);
    if (lane == 0) ws[wid] = v;
    __syncthreads();
    if (threadIdx.x == 0) bsum[blockIdx.x] = ws[0]+ws[1]+ws[2]+ws[3];
}

__global__ __launch_bounds__(256) void scan_phase2(const int* __restrict__ bsum,
                                                   int* __restrict__ bbase){
    __shared__ int ws[4];
    const int t = threadIdx.x;
    const int lane = t & 63, wid = t >> 6;
    int v = (t < SCAN_B) ? bsum[t] : 0;
    int incl = v;
    #pragma unroll
    for (int off = 1; off < 64; off <<= 1){
        const int u = __shfl_up(incl, off, 64);
        if (lane >= off) incl += u;
    }
    if (lane == 63) ws[wid] = incl;
    __syncthreads();
    int wb = 0;
    for (int j = 0; j < wid; ++j) wb += ws[j];
    if (t < SCAN_B) bbase[t] = wb + incl - v;   // exclusive
}

__global__ __launch_bounds__(256) void scan_phase3(const int* __restrict__ counts,
                                                   const int* __restrict__ bbase,
                                                   int* __restrict__ offsets,
                                                   int* __restrict__ cursor){
    __shared__ int ws[4];
    const int idx = blockIdx.x*256 + threadIdx.x;
    const int lane = threadIdx.x & 63, wid = threadIdx.x >> 6;
    const int v = (idx < N_NODES) ? counts[idx] : 0;
    int incl = v;
    #pragma unroll
    for (int off = 1; off < 64; off <<= 1){
        const int u = __shfl_up(incl, off, 64);
        if (lane >= off) incl += u;
    }
    if (lane == 63) ws[wid] = incl;
    __syncthreads();
    int wb = bbase[blockIdx.x];
    for (int j = 0; j < wid; ++j) wb += ws[j];
    const int excl = wb + incl - v;
    if (idx < N_NODES){
        offsets[idx] = excl; cursor[idx] = excl;
        if (idx == N_NODES-1) offsets[N_NODES] = excl + v;
    }
}

// edges[pos] = (src*1536 byte offset into P, eav bits)
__global__ __launch_bounds__(256) void scatter_kernel(
    const int* __restrict__ ei, const void* __restrict__ ea,
    int* __restrict__ cursor, int2* __restrict__ edges,
    const int* __restrict__ flags){
    const int e = blockIdx.x*256 + threadIdx.x;
    if (e >= N_EDGES) return;
    const bool i64 = flags[0] != 0, f32 = flags[1] != 0;
    const int src = i64 ? ((const int2*)ei)[e].x           : ei[e];
    const int dst = i64 ? ((const int2*)ei)[N_EDGES + e].x : ei[N_EDGES + e];
    if ((unsigned)src >= N_NODES || (unsigned)dst >= N_NODES) return;
    const float eav = f32 ? ((const float*)ea)[e] : b2f(((const bf16*)ea)[e]);
    const int pos = atomicAdd(&cursor[dst], 1);
    edges[pos] = make_int2(src * 1536, __float_as_int(eav));
}

// ---- transpose 4 weight mats [K,256] -> Wt[1024][K] bf16, biases -> f32 ----
template<int K>
__global__ __launch_bounds__(256) void trans_w(
    const void* w0, const void* w1, const void* w2, const void* w3,
    const void* b0, const void* b1, const void* b2, const void* b3,
    bf16* __restrict__ Wt, float* __restrict__ biasf,
    const int* __restrict__ flags)
{
    const bool f32 = flags[1] != 0;
    const int mi = blockIdx.y;
    const void* W = mi==0?w0 : mi==1?w1 : mi==2?w2 : w3;
    const void* B = mi==0?b0 : mi==1?b1 : mi==2?b2 : b3;
    const int t = threadIdx.x;
    if (blockIdx.x == 0) biasf[mi*256 + t] = ldrt(B, t, f32);
    if (t >= K) return;
    const int c0 = blockIdx.x * 16;
    for (int c = c0; c < c0 + 16; ++c)
        Wt[(size_t)(mi*256 + c)*K + t] = f2b(ldrt(W, (size_t)t*256 + c, f32));
}

// ---- MFMA GEMM (128x128 tile, 4 waves, 4x4 MFMA tiles per wave) ------------
// P[:, 0:768] = X@W(qkv)+b (row stride 768); cols 768..1023 -> skipb [N,256]
#define AST2 40   // LDS row stride in shorts (32 data + 8 pad -> 2-way max)
template<int K>
__global__ __launch_bounds__(256) void gemm_qkvs(
    const bf16* __restrict__ X, const bf16* __restrict__ Wt,
    const float* __restrict__ bias,
    bf16* __restrict__ P, bf16* __restrict__ skipb)
{
    __shared__ short As[128*AST2];
    __shared__ short Bs[128*AST2];
    const int t = threadIdx.x;
    const int wave = t >> 6, lane = t & 63;
    const int quad = lane >> 4, l16 = lane & 15;
    const int wm = wave >> 1, wn = wave & 1;       // 2x2 wave grid
    const int m0 = blockIdx.x * 128;
    const int n0 = blockIdx.y * 128;
    const int srow = t >> 1;                        // 0..127
    const int scol = (t & 1) * 16;                  // 0 or 16
    const int arow = m0 + srow;
    const int brow = n0 + srow;                     // always < 1024

    frag_cd acc[4][4] = {};
    for (int k0 = 0; k0 < K; k0 += 32){
        uint4 a0 = {0,0,0,0}, a1 = {0,0,0,0};
        if (arow < N_NODES){
            a0 = *(const uint4*)(X + (size_t)arow*K + k0 + scol);
            a1 = *(const uint4*)(X + (size_t)arow*K + k0 + scol + 8);
        }
        const uint4 b0 = *(const uint4*)(Wt + (size_t)brow*K + k0 + scol);
        const uint4 b1 = *(const uint4*)(Wt + (size_t)brow*K + k0 + scol + 8);
        __syncthreads();                            // prev reads done
        *(uint4*)&As[srow*AST2 + scol]     = a0;
        *(uint4*)&As[srow*AST2 + scol + 8] = a1;
        *(uint4*)&Bs[srow*AST2 + scol]     = b0;
        *(uint4*)&Bs[srow*AST2 + scol + 8] = b1;
        __syncthreads();
        frag_ab af[4], bfm[4];
        #pragma unroll
        for (int i = 0; i < 4; ++i){
            af[i]  = *(const frag_ab*)&As[(wm*64 + i*16 + l16)*AST2 + quad*8];
            bfm[i] = *(const frag_ab*)&Bs[(wn*64 + i*16 + l16)*AST2 + quad*8];
        }
        #pragma unroll
        for (int mt = 0; mt < 4; ++mt)
            #pragma unroll
            for (int nt = 0; nt < 4; ++nt)
                acc[mt][nt] = __builtin_amdgcn_mfma_f32_16x16x32_bf16(
                    af[mt], bfm[nt], acc[mt][nt], 0, 0, 0);
    }
    #pragma unroll
    for (int mt = 0; mt < 4; ++mt){
        #pragma unroll
        for (int nt = 0; nt < 4; ++nt){
            const int gc = n0 + wn*64 + nt*16 + l16;       // 0..1023
            const float bsum = bias[gc];
            #pragma unroll
            for (int r = 0; r < 4; ++r){
                const int node = m0 + wm*64 + mt*16 + quad*4 + r;
                if (node < N_NODES){
                    const float y = acc[mt][nt][r] + bsum;
                    if (gc < 768) P[(size_t)node*768 + gc] = f2b(y);
                    else          skipb[(size_t)node*256 + (gc - 768)] = f2b(y);
                }
            }
        }
    }
}

// ---- fused per-node attention + softmax + skip + LN (+ReLU) ----------------
// One wave per dst node; lane owns channels c = lane*4..+3.
// Algebra: q.(k+eav*ew) = q.k + eav*(q.ew);  sum a*(v+eav*ew) = sum a*v + ew*sum(a*eav)
template<int HEADS, bool RELU, bool OUTDYN>
__global__ __launch_bounds__(256) void node_attn(
    const bf16* __restrict__ P,          // [N,768] q|k|v
    const int2* __restrict__ edges,      // dst-sorted (src*1536, eav)
    const int* __restrict__ offsets,     // [N+1]
    const bf16* __restrict__ skip,       // [N,256]
    const float* __restrict__ ewf,
    const float* __restrict__ gf, const float* __restrict__ bf_,
    void* __restrict__ out, const int* __restrict__ flags)
{
    const int node = blockIdx.x*4 + (threadIdx.x >> 6);
    if (node >= N_NODES) return;
    const int lane = threadIdx.x & 63;
    const int c0 = lane * 4;
    const float scale = (HEADS == 4) ? 0.125f : 0.0625f;
    const int RED = (HEADS == 4) ? 16 : 64;

    float q4[4], ew4[4];
    ld4bf(P + (size_t)node*768 + c0, q4);
    ew4[0] = ewf[c0]; ew4[1] = ewf[c0+1]; ew4[2] = ewf[c0+2]; ew4[3] = ewf[c0+3];

    float qe = q4[0]*ew4[0] + q4[1]*ew4[1] + q4[2]*ew4[2] + q4[3]*ew4[3];
    #pragma unroll
    for (int off = 1; off < 64; off <<= 1)
        if (off < RED) qe += __shfl_xor(qe, off, 64);
    const float qewS = qe * scale;

    const int beg = offsets[node], end = offsets[node+1];
    float s = 0.f, seav = 0.f;
    float macc[4] = {0.f, 0.f, 0.f, 0.f};

    const char* base = (const char*)P + 512 + 2*c0;   // + src*1536 -> k chans c0..
    if (beg < end){
        int2 rec = edges[beg];
        uint2 ku = *(const uint2*)(base + (size_t)(unsigned)rec.x);
        uint2 vu = *(const uint2*)(base + (size_t)(unsigned)rec.x + 512);
        for (int e = beg; e < end; ++e){
            const int2 nrec = (e + 1 < end) ? edges[e+1] : rec;
            const uint2 ku2 = *(const uint2*)(base + (size_t)(unsigned)nrec.x);
            const uint2 vu2 = *(const uint2*)(base + (size_t)(unsigned)nrec.x + 512);
            const float eav = __int_as_float(rec.y);
            float kf[4];
            ld4dec(ku, kf);
            float p = q4[0]*kf[0] + q4[1]*kf[1] + q4[2]*kf[2] + q4[3]*kf[3];
            #pragma unroll
            for (int off = 1; off < 64; off <<= 1)
                if (off < RED) p += __shfl_xor(p, off, 64);
            const float a = expf(fminf(fmaf(p, scale, eav*qewS), 80.f));
            s += a;
            seav = fmaf(a, eav, seav);
            float vf[4];
            ld4dec(vu, vf);
            macc[0] = fmaf(a, vf[0], macc[0]);
            macc[1] = fmaf(a, vf[1], macc[1]);
            macc[2] = fmaf(a, vf[2], macc[2]);
            macc[3] = fmaf(a, vf[3], macc[3]);
            rec = nrec; ku = ku2; vu = vu2;
        }
    }

    const float rdenom = 1.f / (s + 1e-16f);
    float sk[4];
    ld4bf(skip + (size_t)node*256 + c0, sk);
    float val[4];
    #pragma unroll
    for (int j = 0; j < 4; ++j)
        val[j] = fmaf(ew4[j], seav, macc[j]) * rdenom + sk[j];

    float sum = val[0]+val[1]+val[2]+val[3];
    #pragma unroll
    for (int off = 1; off < 64; off <<= 1) sum += __shfl_xor(sum, off, 64);
    const float mu = sum * (1.f/256.f);
    float vs = 0.f;
    #pragma unroll
    for (int j = 0; j < 4; ++j){ const float d = val[j]-mu; vs += d*d; }
    #pragma unroll
    for (int off = 1; off < 64; off <<= 1) vs += __shfl_xor(vs, off, 64);
    const float rstd = rsqrtf(vs * (1.f/256.f) + 1e-5f);

    float y[4];
    #pragma unroll
    for (int j = 0; j < 4; ++j){
        y[j] = (val[j]-mu) * rstd * gf[c0+j] + bf_[c0+j];
        if (RELU) y[j] = fmaxf(y[j], 0.f);
    }
    const bool of32 = OUTDYN && (flags[1] != 0);
    if (of32){
        float4 o = {y[0], y[1], y[2], y[3]};
        *(float4*)((float*)out + (size_t)node*256 + c0) = o;
    } else {
        uint2 o;
        o.x = ((unsigned)__bfloat16_as_ushort(f2b(y[0]))) |
              (((unsigned)__bfloat16_as_ushort(f2b(y[1]))) << 16);
        o.y = ((unsigned)__bfloat16_as_ushort(f2b(y[2]))) |
              (((unsigned)__bfloat16_as_ushort(f2b(y[3]))) << 16);
        *(uint2*)((bf16*)out + (size_t)node*256 + c0) = o;
    }
}

extern "C" void kernel_launch(void* const* d_in, const int* in_sizes, int n_in,
                              void* d_out, int out_size, void* d_ws, size_t ws_size,
                              hipStream_t stream) {
    const int* ei = (const int*)d_in[1];

    // ---- workspace layout (bytes), peak ~110 MB ----
    char* w = (char*)d_ws;
    bf16*  P       = (bf16*) (w + 0);            // [N,768] (76.8MB)
    bf16*  xb      = (bf16*) (w + 76800000);     // [N,128] (dead after GEMM0)
    bf16*  skipL1  = (bf16*) (w + 76800000);     // [N,256] (born at GEMM1)
    bf16*  Wt      = (bf16*) (w + 102400000);    // 1024*256*2 = 524288
    float* biasf   = (float*)(w + 102924288);    // 4KB
    int*   counts  = (int*)  (w + 102928384);    // 200KB
    int*   offsets = (int*)  (w + 103128384);    // 200KB+4
    int*   cursor  = (int*)  (w + 103328388);    // 200KB
    int2*  edges   = (int2*) (w + 103528392);    // 6.4MB
    float* vecs    = (float*)(w + 109928400);    // 6x256 f32
    int*   flags   = (int*)  (w + 109934544);
    int*   bsum    = (int*)  (w + 109934608);    // SCAN_B ints
    int*   bbase   = (int*)  (w + 109935392);    // SCAN_B ints
    float* ewf0 = vecs + 0,   *ewf1 = vecs + 256;
    float* gf0  = vecs + 512, *bf0  = vecs + 768;
    float* gf1  = vecs + 1024,*bf1  = vecs + 1280;
    bf16*  skipL0 = (bf16*)d_out;   // d_out as scratch: skip -> h in-place
    bf16*  hbuf   = (bf16*)d_out;

    const int EB = (N_EDGES + 255) / 256;
    const int NB = (N_NODES + 3) / 4;

    detect_kernel<<<1, 256, 0, stream>>>(ei, (const unsigned int*)d_in[0], flags);
    hipMemsetAsync(counts, 0, (size_t)N_NODES*4, stream);
    conv_x<<<3125, 256, 0, stream>>>(d_in[0], xb, flags);
    conv_vec6<<<1, 256, 0, stream>>>(d_in[9], d_in[20], d_in[12], d_in[13],
                                     d_in[23], d_in[24], vecs, flags);
    // CSR build (once, shared by both layers)
    hist_kernel<<<EB, 256, 0, stream>>>(ei, counts, flags);
    scan_phase1<<<SCAN_B, 256, 0, stream>>>(counts, bsum);
    scan_phase2<<<1, 256, 0, stream>>>(bsum, bbase);
    scan_phase3<<<SCAN_B, 256, 0, stream>>>(counts, bbase, offsets, cursor);
    scatter_kernel<<<EB, 256, 0, stream>>>(ei, d_in[2], cursor, edges, flags);

    // ---------------- layer 0 ----------------
    trans_w<128><<<dim3(16,4), 256, 0, stream>>>(
        d_in[3], d_in[5], d_in[7], d_in[10],
        d_in[4], d_in[6], d_in[8], d_in[11],
        Wt, biasf, flags);
    gemm_qkvs<128><<<dim3(391,8), 256, 0, stream>>>(xb, Wt, biasf, P, skipL0);
    node_attn<4, true, false><<<NB, 256, 0, stream>>>(
        P, edges, offsets, skipL0, ewf0, gf0, bf0, hbuf, flags);

    // ---------------- layer 1 ----------------
    trans_w<256><<<dim3(16,4), 256, 0, stream>>>(
        d_in[14], d_in[16], d_in[18], d_in[21],
        d_in[15], d_in[17], d_in[19], d_in[22],
        Wt, biasf, flags);
    gemm_qkvs<256><<<dim3(391,8), 256, 0, stream>>>(hbuf, Wt, biasf, P, skipL1);
    node_attn<1, false, true><<<NB, 256, 0, stream>>>(
        P, edges, offsets, skipL1, ewf1, gf1, bf1, d_out, flags);
}